// Round 19
// baseline (1630.120 us; speedup 1.0000x reference)
//
#include <hip/hip_runtime.h>
#include <math.h>

using u16 = unsigned short;
using u32 = unsigned int;

constexpr int Bc = 16;     // batch
constexpr int Tc = 64;     // tokens == prefixes
constexpr int INc = 128;
constexpr int Dc = 512;
constexpr int Hc = 8;
constexpr int Fc = 2048;
constexpr int Lc = 4;
constexpr float SCALEc = 0.125f;  // 1/sqrt(64)

// Compacted triangular layout with 8-aligned (p,b) segments. TWO groups.
constexpr int NGc = 2;
constexpr int g_p0[NGc]   = {0, 44};
constexpr int g_np[NGc]   = {44, 20};
constexpr int g_start[NGc]= {0, 18432};
constexpr int g_M[NGc]    = {18432, 18432};   // rows (%128==0, no padding)
constexpr int g_M3[NGc]   = {768, 384};       // per-group qd GEMM M (%128)
constexpr int g_doff[NGc] = {0, 704};         // diag row offsets (packed)
constexpr int GMAXc = 18432;
constexpr int DALLc = 1024;          // total diag rows (704+320)
constexpr int DPADc = 1152;          // diag buffers incl. qd-GEMM overrun
constexpr int VTSc  = GMAXc + 64;    // vt row stride (slack for over-read)

typedef __attribute__((ext_vector_type(8))) short bf16x8;
typedef __attribute__((ext_vector_type(4))) float f32x4;

__device__ __forceinline__ int rowbase(int p) {  // C(p)
  const int q = p >> 3, r = p & 7;
  return 128 * (4 * q * (q + 1) + r * (q + 1));
}

__device__ __forceinline__ float bf2f(u16 u) {
  union { u32 i; float f; } c; c.i = (u32)u << 16; return c.f;
}
__device__ __forceinline__ u16 f2bf(float f) {
  union { float f; u32 u; } c{f};
  u32 r = (c.u + 0x7fffu + ((c.u >> 16) & 1u)) >> 16;
  return (u16)r;
}

// ---------------------------------------------------------------------------
// fp32 -> bf16 convert (x input)
// ---------------------------------------------------------------------------
__global__ __launch_bounds__(256) void conv_bf16(
    const float* __restrict__ x, u16* __restrict__ xb, int n)
{
  const int i = (blockIdx.x * 256 + threadIdx.x) * 4;
  if (i < n) {
    const float4 v = *(const float4*)(x + i);
    uint2 pk;
    pk.x = (u32)f2bf(v.x) | ((u32)f2bf(v.y) << 16);
    pk.y = (u32)f2bf(v.z) | ((u32)f2bf(v.w) << 16);
    *(uint2*)(xb + i) = pk;
  }
}

// ---------------------------------------------------------------------------
// Weight convert+transpose, multi-layer (grid.z = layer):
// src fp32 [K][N] -> dst bf16 [N][K], per-layer strides.
// ---------------------------------------------------------------------------
__global__ __launch_bounds__(256) void transpose_conv4(
    const float* __restrict__ src0, u16* __restrict__ dst0, int K, int N,
    size_t sstride, size_t dstride)
{
  const float* src = src0 + (size_t)blockIdx.z * sstride;
  u16* dst = dst0 + (size_t)blockIdx.z * dstride;
  __shared__ float t[32][33];
  const int bx = blockIdx.x * 32;
  const int by = blockIdx.y * 32;
  const int x = threadIdx.x, y = threadIdx.y;  // 32 x 8
#pragma unroll
  for (int i = 0; i < 32; i += 8) t[y + i][x] = src[(size_t)(by + y + i) * N + bx + x];
  __syncthreads();
#pragma unroll
  for (int i = 0; i < 32; i += 8)
    dst[(size_t)(bx + y + i) * K + by + x] = f2bf(t[x][y + i]);
}

// ---------------------------------------------------------------------------
// V transpose: qkvsrc[r][1024+d] (stride 1536) -> vt[d][r], 64x64 LDS tiles.
// ---------------------------------------------------------------------------
__global__ __launch_bounds__(256) void transpose_v(
    const u16* __restrict__ qkvsrc, u16* __restrict__ vt, int vstride)
{
  __shared__ u16 t[64][65];
  const int r0 = blockIdx.x * 64;
  const int d0 = blockIdx.y * 64;
  const int tid = threadIdx.x;
  const int rr = tid >> 2, cc = (tid & 3) * 16;
  const u16* src = qkvsrc + (size_t)(r0 + rr) * 1536 + 1024 + d0 + cc;
  union { uint4 v; u16 s[8]; } ua, ub;
  ua.v = *(const uint4*)src;
  ub.v = *(const uint4*)(src + 8);
#pragma unroll
  for (int i = 0; i < 8; ++i) { t[rr][cc + i] = ua.s[i]; t[rr][cc + 8 + i] = ub.s[i]; }
  __syncthreads();
  const int dd = tid >> 2, kk = (tid & 3) * 16;
  union { uint4 v; u16 s[8]; } w0, w1;
#pragma unroll
  for (int i = 0; i < 8; ++i) { w0.s[i] = t[kk + i][dd]; w1.s[i] = t[kk + 8 + i][dd]; }
  u16* dst = vt + (size_t)(d0 + dd) * vstride + r0 + kk;
  *(uint4*)dst = w0.v;
  *(uint4*)(dst + 8) = w1.v;
}

// ---------------------------------------------------------------------------
// LDS staging helpers (pre-swizzled SOURCE, linear dest).
// ---------------------------------------------------------------------------
__device__ __forceinline__ void stage_tile(const u16* __restrict__ src, int ldk, u16* lds)
{
  const int tid = threadIdx.x;
#pragma unroll
  for (int q = 0; q < 4; ++q) {
    const int p16 = tid + (q << 8);
    const int row = p16 >> 3;
    const int s   = p16 & 7;
    const int k16 = s ^ (row & 7);
    const u16* g = src + (size_t)row * ldk + (k16 << 3);
    __builtin_amdgcn_global_load_lds(
        (const __attribute__((address_space(1))) void*)g,
        (__attribute__((address_space(3))) void*)(lds + (p16 << 3)),
        16, 0, 0);
  }
}

__device__ __forceinline__ void stage_tile64(const u16* __restrict__ src, int ldk, u16* lds)
{
  const int tid = threadIdx.x;
#pragma unroll
  for (int q = 0; q < 2; ++q) {
    const int p16 = tid + (q << 8);      // 512 granules: 64 rows x 8
    const int row = p16 >> 3;
    const int s   = p16 & 7;
    const int k16 = s ^ (row & 7);
    const u16* g = src + (size_t)row * ldk + (k16 << 3);
    __builtin_amdgcn_global_load_lds(
        (const __attribute__((address_space(1))) void*)g,
        (__attribute__((address_space(3))) void*)(lds + (p16 << 3)),
        16, 0, 0);
  }
}

// ---------------------------------------------------------------------------
// bf16 MFMA GEMM: 128x128 tile, BK=64, dbuf, counted vmcnt(8).
// Used for the wide-N GEMMs (qkv N=1536, ff1 N=2048, kv3 N=1024).
// ---------------------------------------------------------------------------
template<bool RELU, bool OUT_BF16>
__global__ __launch_bounds__(256) void gemm_mfma(
    const u16* __restrict__ A, const u16* __restrict__ Wt,
    const float* __restrict__ bias, void* __restrict__ Cout,
    int M, int K, int N)
{
  __shared__ u16 As[2][128 * 64];
  __shared__ u16 Bs[2][128 * 64];

  const int tid  = threadIdx.x;
  const int lane = tid & 63;
  const int wave = tid >> 6;
  const int wr = wave >> 1;
  const int wc = wave & 1;

  const int gx = gridDim.x;
  const int nwg = gx * gridDim.y;
  const int lin = blockIdx.y * gx + blockIdx.x;
  const int qq = nwg >> 3, r8 = nwg & 7;
  const int xcd = lin & 7, pos = lin >> 3;
  const int orig = (xcd < r8) ? (xcd * (qq + 1) + pos)
                              : (r8 * (qq + 1) + (xcd - r8) * qq + pos);
  const int row0 = (orig / gx) * 128;
  const int col0 = (orig % gx) * 128;

  f32x4 acc[4][4];
#pragma unroll
  for (int i = 0; i < 4; ++i)
#pragma unroll
    for (int j = 0; j < 4; ++j) acc[i][j] = f32x4{0.f, 0.f, 0.f, 0.f};

  const int nk = K >> 6;
  const int arow = wr * 64 + (lane & 15);
  const int brow = wc * 64 + (lane & 15);
  const int kq   = lane >> 4;

  stage_tile(A  + (size_t)row0 * K, K, &As[0][0]);
  stage_tile(Wt + (size_t)col0 * K, K, &Bs[0][0]);

  for (int t = 0; t < nk; ++t) {
    const int cur = t & 1;
    if (t + 1 < nk) {
      const int k0 = (t + 1) << 6;
      stage_tile(A  + (size_t)row0 * K + k0, K, &As[cur ^ 1][0]);
      stage_tile(Wt + (size_t)col0 * K + k0, K, &Bs[cur ^ 1][0]);
      asm volatile("s_waitcnt vmcnt(8)\n\ts_barrier" ::: "memory");
    } else {
      asm volatile("s_waitcnt vmcnt(0)\n\ts_barrier" ::: "memory");
    }
    const u16* Ab = &As[cur][0];
    const u16* Bb = &Bs[cur][0];
#pragma unroll
    for (int kk = 0; kk < 2; ++kk) {
      bf16x8 af[4], bfr[4];
      const int c = kk * 4 + kq;
#pragma unroll
      for (int i = 0; i < 4; ++i) {
        const int ra = arow + i * 16;
        af[i]  = *reinterpret_cast<const bf16x8*>(Ab + ra * 64 + ((c ^ (ra & 7)) << 3));
        const int rb = brow + i * 16;
        bfr[i] = *reinterpret_cast<const bf16x8*>(Bb + rb * 64 + ((c ^ (rb & 7)) << 3));
      }
#pragma unroll
      for (int mi = 0; mi < 4; ++mi)
#pragma unroll
        for (int ni = 0; ni < 4; ++ni)
          acc[mi][ni] = __builtin_amdgcn_mfma_f32_16x16x32_bf16(af[mi], bfr[ni], acc[mi][ni], 0, 0, 0);
    }
    asm volatile("s_barrier" ::: "memory");
  }

  const int r0 = row0 + wr * 64 + ((lane >> 4) << 2);
  const int c0 = col0 + wc * 64 + (lane & 15);
#pragma unroll
  for (int mi = 0; mi < 4; ++mi)
#pragma unroll
    for (int ni = 0; ni < 4; ++ni) {
      const int col = c0 + ni * 16;
      const float bsv = bias[col];
#pragma unroll
      for (int j = 0; j < 4; ++j) {
        const int row = r0 + mi * 16 + j;
        float o = acc[mi][ni][j] + bsv;
        if (RELU) o = fmaxf(o, 0.f);
        if (OUT_BF16) ((u16*)Cout)[(size_t)row * N + col] = f2bf(o);
        else          ((float*)Cout)[(size_t)row * N + col] = o;
      }
    }
}

// ---------------------------------------------------------------------------
// Narrow-N GEMM: 128x64 tile, BK=64, THREE-buffer ring, SINGLE fused
// vmcnt(6)+barrier per K-step, 2-tile-deep prefetch. 72 KB LDS -> 2 blk/CU.
// Safety: barrier(t) implies all waves consumed buf[(t-1)%3] (ds_read data
// is in regs before barrier arrival), so stage(t+2) into that buffer after
// the barrier is race-free. vmcnt(6) leaves stage(t+1) in flight.
// ---------------------------------------------------------------------------
template<bool RELU, bool OUT_BF16>
__global__ __launch_bounds__(256) void gemm_mfma_n64(
    const u16* __restrict__ A, const u16* __restrict__ Wt,
    const float* __restrict__ bias, void* __restrict__ Cout,
    int M, int K, int N)
{
  __shared__ u16 As[3][128 * 64];
  __shared__ u16 Bs[3][64 * 64];

  const int tid  = threadIdx.x;
  const int lane = tid & 63;
  const int wave = tid >> 6;        // 0..3, each owns 32 rows x 64 cols

  const int gx = gridDim.x;
  const int nwg = gx * gridDim.y;
  const int lin = blockIdx.y * gx + blockIdx.x;
  const int qq = nwg >> 3, r8 = nwg & 7;
  const int xcd = lin & 7, pos = lin >> 3;
  const int orig = (xcd < r8) ? (xcd * (qq + 1) + pos)
                              : (r8 * (qq + 1) + (xcd - r8) * qq + pos);
  const int row0 = (orig / gx) * 128;
  const int col0 = (orig % gx) * 64;

  f32x4 acc[2][4];
#pragma unroll
  for (int i = 0; i < 2; ++i)
#pragma unroll
    for (int j = 0; j < 4; ++j) acc[i][j] = f32x4{0.f, 0.f, 0.f, 0.f};

  const int nk = K >> 6;
  const int arow = wave * 32 + (lane & 15);
  const int brow = lane & 15;
  const int kq   = lane >> 4;

  // prologue: stage tiles 0 and 1
  stage_tile  (A  + (size_t)row0 * K, K, &As[0][0]);
  stage_tile64(Wt + (size_t)col0 * K, K, &Bs[0][0]);
  if (nk > 1) {
    stage_tile  (A  + (size_t)row0 * K + 64, K, &As[1][0]);
    stage_tile64(Wt + (size_t)col0 * K + 64, K, &Bs[1][0]);
  }

  int cur = 0;
  for (int t = 0; t < nk; ++t) {
    if (t + 1 < nk) {
      asm volatile("s_waitcnt vmcnt(6)\n\ts_barrier" ::: "memory");
    } else {
      asm volatile("s_waitcnt vmcnt(0)\n\ts_barrier" ::: "memory");
    }
    if (t + 2 < nk) {
      const int k0 = (t + 2) << 6;
      const int nb = (t + 2) % 3;
      stage_tile  (A  + (size_t)row0 * K + k0, K, &As[nb][0]);
      stage_tile64(Wt + (size_t)col0 * K + k0, K, &Bs[nb][0]);
    }
    const u16* Ab = &As[cur][0];
    const u16* Bb = &Bs[cur][0];
#pragma unroll
    for (int kk = 0; kk < 2; ++kk) {
      bf16x8 af[2], bfr[4];
      const int c = kk * 4 + kq;
#pragma unroll
      for (int i = 0; i < 2; ++i) {
        const int ra = arow + i * 16;
        af[i] = *reinterpret_cast<const bf16x8*>(Ab + ra * 64 + ((c ^ (ra & 7)) << 3));
      }
#pragma unroll
      for (int i = 0; i < 4; ++i) {
        const int rb = brow + i * 16;
        bfr[i] = *reinterpret_cast<const bf16x8*>(Bb + rb * 64 + ((c ^ (rb & 7)) << 3));
      }
#pragma unroll
      for (int mi = 0; mi < 2; ++mi)
#pragma unroll
        for (int ni = 0; ni < 4; ++ni)
          acc[mi][ni] = __builtin_amdgcn_mfma_f32_16x16x32_bf16(af[mi], bfr[ni], acc[mi][ni], 0, 0, 0);
    }
    cur = (cur == 2) ? 0 : cur + 1;
  }

  const int r0 = row0 + wave * 32 + ((lane >> 4) << 2);
  const int c0 = col0 + (lane & 15);
#pragma unroll
  for (int mi = 0; mi < 2; ++mi)
#pragma unroll
    for (int ni = 0; ni < 4; ++ni) {
      const int col = c0 + ni * 16;
      const float bsv = bias[col];
#pragma unroll
      for (int j = 0; j < 4; ++j) {
        const int row = r0 + mi * 16 + j;
        float o = acc[mi][ni][j] + bsv;
        if (RELU) o = fmaxf(o, 0.f);
        if (OUT_BF16) ((u16*)Cout)[(size_t)row * N + col] = f2bf(o);
        else          ((float*)Cout)[(size_t)row * N + col] = o;
      }
    }
}

// ---------------------------------------------------------------------------
// MFMA flash attention. One 64-lane wave per (head, b, p).
// ---------------------------------------------------------------------------
template<bool SHARED>
__global__ __launch_bounds__(64) void attn_mfma_kernel(
    const u16* __restrict__ qkv, const u16* __restrict__ vt, int vstride,
    u16* __restrict__ attno, int p0, int gstart)
{
  const int hh = blockIdx.x, b = blockIdx.y, p = p0 + blockIdx.z;
  const int NT = p + 1;
  const int NT8 = (NT + 7) & ~7;
  const int rb = rowbase(p) + b * NT8 - gstart;   // output row base
  const int sb = SHARED ? (b * 64) : rb;          // source row base
  const int tid = threadIdx.x;
  const int lc = tid & 15, lg = tid >> 4;

  __shared__ u16 Plds[64][72];     // P[q][k]
  __shared__ u16 VTl[4096];        // V^T [d][k], 16B-granule swizzled
  __shared__ float invl[64];

  {
    const u16* vbase = vt + (size_t)(hh * 64) * vstride + sb;
#pragma unroll
    for (int it = 0; it < 8; ++it) {
      const int gi = tid + (it << 6);
      const int dd = gi >> 3, s = gi & 7;
      const u16* src = vbase + (size_t)dd * vstride + ((s ^ (dd & 7)) << 3);
      __builtin_amdgcn_global_load_lds(
          (const __attribute__((address_space(1))) void*)src,
          (__attribute__((address_space(3))) void*)(&VTl[gi << 3]), 16, 0, 0);
    }
  }

  f32x4 st[4][4];
#pragma unroll
  for (int i = 0; i < 4; ++i)
#pragma unroll
    for (int j = 0; j < 4; ++j) st[i][j] = f32x4{0.f, 0.f, 0.f, 0.f};

#pragma unroll
  for (int kt = 0; kt < 2; ++kt) {
    bf16x8 kf[4], qf[4];
#pragma unroll
    for (int t = 0; t < 4; ++t) {
      if (t * 16 < NT) {
        const size_t rbase = (size_t)(sb + t * 16 + lc) * 1536 + hh * 64 + kt * 32 + lg * 8;
        qf[t] = *reinterpret_cast<const bf16x8*>(qkv + rbase);
        kf[t] = *reinterpret_cast<const bf16x8*>(qkv + rbase + 512);
      }
    }
#pragma unroll
    for (int mi = 0; mi < 4; ++mi)
      if (mi * 16 < NT)
#pragma unroll
        for (int ni = 0; ni < 4; ++ni)
          if (ni * 16 < NT)
            st[mi][ni] = __builtin_amdgcn_mfma_f32_16x16x32_bf16(kf[mi], qf[ni], st[mi][ni], 0, 0, 0);
  }

#pragma unroll
  for (int ni = 0; ni < 4; ++ni) {
    float mm = -3.0e38f;
#pragma unroll
    for (int mi = 0; mi < 4; ++mi)
#pragma unroll
      for (int e = 0; e < 4; ++e)
        if (16 * mi + 4 * lg + e < NT) mm = fmaxf(mm, st[mi][ni][e]);
    mm = fmaxf(mm, __shfl_xor(mm, 16));
    mm = fmaxf(mm, __shfl_xor(mm, 32));
    float ss = 0.f;
#pragma unroll
    for (int mi = 0; mi < 4; ++mi) {
      u16 pb[4];
#pragma unroll
      for (int e = 0; e < 4; ++e) {
        const float pe = (16 * mi + 4 * lg + e < NT)
                           ? __expf((st[mi][ni][e] - mm) * SCALEc) : 0.f;
        ss += pe;
        pb[e] = f2bf(pe);
      }
      uint2 pk;
      pk.x = (u32)pb[0] | ((u32)pb[1] << 16);
      pk.y = (u32)pb[2] | ((u32)pb[3] << 16);
      *reinterpret_cast<uint2*>(&Plds[16 * ni + lc][16 * mi + 4 * lg]) = pk;
    }
    ss += __shfl_xor(ss, 16);
    ss += __shfl_xor(ss, 32);
    if (lg == 0) invl[16 * ni + lc] = 1.f / ss;
  }

  asm volatile("s_waitcnt vmcnt(0)" ::: "memory");
  __syncthreads();

  f32x4 oc[4][4];
#pragma unroll
  for (int i = 0; i < 4; ++i)
#pragma unroll
    for (int j = 0; j < 4; ++j) oc[i][j] = f32x4{0.f, 0.f, 0.f, 0.f};

#pragma unroll
  for (int kt = 0; kt < 2; ++kt) {
    if (kt * 32 < NT) {
      bf16x8 pa[4], vbf[4];
#pragma unroll
      for (int t = 0; t < 4; ++t) {
        if (t * 16 < NT)
          pa[t] = *reinterpret_cast<const bf16x8*>(&Plds[t * 16 + lc][kt * 32 + lg * 8]);
        const int dd = t * 16 + lc;
        vbf[t] = *reinterpret_cast<const bf16x8*>(
            &VTl[dd * 64 + (((4 * kt + lg) ^ (lc & 7)) << 3)]);
      }
#pragma unroll
      for (int qt = 0; qt < 4; ++qt)
        if (qt * 16 < NT)
#pragma unroll
          for (int dt = 0; dt < 4; ++dt)
            oc[qt][dt] = __builtin_amdgcn_mfma_f32_16x16x32_bf16(pa[qt], vbf[dt], oc[qt][dt], 0, 0, 0);
    }
  }

#pragma unroll
  for (int qt = 0; qt < 4; ++qt) {
    if (qt * 16 < NT) {
#pragma unroll
      for (int e = 0; e < 4; ++e) {
        const int qrow = qt * 16 + 4 * lg + e;
        if (qrow < NT) {
          const float inv = invl[qrow];
          u16* dst = attno + (size_t)(rb + qrow) * Dc + hh * 64 + lc;
#pragma unroll
          for (int dt = 0; dt < 4; ++dt)
            dst[dt * 16] = f2bf(oc[qt][dt][e] * inv);
        }
      }
    }
  }
}

// ---------------------------------------------------------------------------
// Layer-3 attention: diagonal query only.
// ---------------------------------------------------------------------------
__global__ __launch_bounds__(64) void attn_diag_kernel(
    const u16* __restrict__ kv3, const u16* __restrict__ qd,
    u16* __restrict__ attno_d, int p0, int gstart, int doff)
{
  const int hh = blockIdx.x, b = blockIdx.y, pl = blockIdx.z;
  const int p = p0 + pl;
  const int NT = p + 1;
  const int NT8 = (NT + 7) & ~7;
  const int rb = rowbase(p) + b * NT8 - gstart;
  const int tid = threadIdx.x;
  const int rd = doff + pl * 16 + b;

  __shared__ u16 Ks[64][64];
  __shared__ u16 Vs[64][64];

  const int lrow = tid >> 3;
  const int lc8  = tid & 7;
  for (int t0 = 0; t0 < NT; t0 += 8) {
    const int tr = rb + t0 + lrow;
    const int csrc = (lc8 ^ lrow) << 3;
    const u16* gk = kv3 + (size_t)tr * 1024 + hh * 64 + csrc;
    const u16* gv = kv3 + (size_t)tr * 1024 + 512 + hh * 64 + csrc;
    __builtin_amdgcn_global_load_lds(
        (const __attribute__((address_space(1))) void*)gk,
        (__attribute__((address_space(3))) void*)(&Ks[t0][0] + tid * 8), 16, 0, 0);
    __builtin_amdgcn_global_load_lds(
        (const __attribute__((address_space(1))) void*)gv,
        (__attribute__((address_space(3))) void*)(&Vs[t0][0] + tid * 8), 16, 0, 0);
  }

  const u16* qp = qd + (size_t)rd * Dc + hh * 64;
  float qv[64];
#pragma unroll
  for (int c8 = 0; c8 < 8; ++c8) {
    const bf16x8 q8 = *reinterpret_cast<const bf16x8*>(qp + c8 * 8);
#pragma unroll
    for (int i = 0; i < 8; ++i) qv[c8 * 8 + i] = bf2f((u16)q8[i]);
  }
  asm volatile("s_waitcnt vmcnt(0)" ::: "memory");
  __syncthreads();

  float dot = -1e30f;
  if (tid < NT) {
    dot = 0.f;
#pragma unroll
    for (int c8 = 0; c8 < 8; ++c8) {
      const bf16x8 k8 = *reinterpret_cast<const bf16x8*>(
          &Ks[tid][0] + ((c8 ^ (tid & 7)) << 3));
#pragma unroll
      for (int i = 0; i < 8; ++i) dot += qv[c8 * 8 + i] * bf2f((u16)k8[i]);
    }
    dot *= SCALEc;
  }
  float mm = dot;
#pragma unroll
  for (int off = 32; off; off >>= 1) mm = fmaxf(mm, __shfl_xor(mm, off));
  const float pt = __expf(dot - mm);
  float s = pt;
#pragma unroll
  for (int off = 32; off; off >>= 1) s += __shfl_xor(s, off);
  const float inv = 1.f / s;

  float o = 0.f;   // lane owns output dim d = tid
  for (int t = 0; t < NT; ++t) {
    const float ptt = __shfl(pt, t);
    o += ptt * bf2f(Vs[t][(((tid >> 3) ^ (t & 7)) << 3) + (tid & 7)]);
  }
  attno_d[(size_t)rd * Dc + hh * 64 + tid] = f2bf(o * inv);
}

// ---------------------------------------------------------------------------
// hb = LN(hb + tmpb), bf16 residual carrier. 4 rows/block.
// ---------------------------------------------------------------------------
__device__ inline float wave_sum(float v) {
#pragma unroll
  for (int off = 32; off; off >>= 1) v += __shfl_xor(v, off);
  return v;
}

__global__ __launch_bounds__(256) void res_ln_kernel(
    u16* __restrict__ hb, const u16* __restrict__ tmpb,
    const float* __restrict__ g, const float* __restrict__ bt)
{
  const size_t row = (size_t)blockIdx.x * 4 + (threadIdx.x >> 6);
  const int t = threadIdx.x & 63;
  float v[8];
  float s = 0.f;
#pragma unroll
  for (int i = 0; i < 8; ++i) {
    v[i] = bf2f(hb[row * Dc + i * 64 + t]) + bf2f(tmpb[row * Dc + i * 64 + t]);
    s += v[i];
  }
  s = wave_sum(s);
  const float mean = s * (1.f / 512.f);
  float vs = 0.f;
#pragma unroll
  for (int i = 0; i < 8; ++i) { const float d = v[i] - mean; vs += d * d; }
  vs = wave_sum(vs);
  const float rstd = rsqrtf(vs * (1.f / 512.f) + 1e-5f);
#pragma unroll
  for (int i = 0; i < 8; ++i)
    hb[row * Dc + i * 64 + t] =
        f2bf((v[i] - mean) * rstd * g[i * 64 + t] + bt[i * 64 + t]);
}

// ---------------------------------------------------------------------------
// Fused broadcast + layer-0 LN1: hb = LN(h0b[b,t] + tmpb[row]).
// ---------------------------------------------------------------------------
__global__ __launch_bounds__(64) void res_ln0_kernel(
    const u16* __restrict__ h0b, u16* __restrict__ hb,
    const u16* __restrict__ tmpb, const float* __restrict__ g,
    const float* __restrict__ bt, int p0, int gstart)
{
  const int t = blockIdx.x, b = blockIdx.y, p = p0 + blockIdx.z;
  if (t > p) return;
  const int NT8 = (p + 8) & ~7;
  const size_t row = (size_t)(rowbase(p) + b * NT8 + t - gstart);
  const int tt = threadIdx.x;
  const u16* src = h0b + (size_t)(b * 64 + t) * Dc;
  float v[8];
  float s = 0.f;
#pragma unroll
  for (int i = 0; i < 8; ++i) {
    v[i] = bf2f(src[i * 64 + tt]) + bf2f(tmpb[row * Dc + i * 64 + tt]);
    s += v[i];
  }
  s = wave_sum(s);
  const float mean = s * (1.f / 512.f);
  float vs = 0.f;
#pragma unroll
  for (int i = 0; i < 8; ++i) { const float d = v[i] - mean; vs += d * d; }
  vs = wave_sum(vs);
  const float rstd = rsqrtf(vs * (1.f / 512.f) + 1e-5f);
#pragma unroll
  for (int i = 0; i < 8; ++i)
    hb[row * Dc + i * 64 + tt] =
        f2bf((v[i] - mean) * rstd * g[i * 64 + tt] + bt[i * 64 + tt]);
}

// ---------------------------------------------------------------------------
// Diag gather (bf16 copy)
// ---------------------------------------------------------------------------
__global__ __launch_bounds__(128) void gather_diag(
    const u16* __restrict__ hb, u16* __restrict__ hbd,
    int p0, int gstart, int doff)
{
  const int pl = blockIdx.x >> 4, b = blockIdx.x & 15;
  const int p = p0 + pl;
  const int NT8 = (p + 8) & ~7;
  const size_t src = (size_t)(rowbase(p) + b * NT8 + p - gstart);
  ((uint2*)(hbd + (size_t)(doff + blockIdx.x) * Dc))[threadIdx.x] =
      ((const uint2*)(hb + src * Dc))[threadIdx.x];
}

// ---------------------------------------------------------------------------
// Classifier finish: 2-logit GEMV on ffc (bf16) + log_softmax.
// blockIdx.x = b*64 + p; rd = (p<44) ? p*16+b : 704+(p-44)*16+b.
// ---------------------------------------------------------------------------
__global__ __launch_bounds__(64) void cls_fin_kernel(
    const u16* __restrict__ ffc, const float* __restrict__ w2,
    const float* __restrict__ b2, float* __restrict__ out)
{
  const int row = blockIdx.x;
  const int b = row >> 6, p = row & 63;
  const int rd = (p < 44) ? (p * 16 + b) : (704 + (p - 44) * 16 + b);
  const int t = threadIdx.x;
  float c0 = 0.f, c1 = 0.f;
#pragma unroll
  for (int k = 0; k < 4; ++k) {
    const int j = t + k * 64;
    const float fv = bf2f(ffc[(size_t)rd * 256 + j]);
    c0 += fv * w2[j * 2 + 0];
    c1 += fv * w2[j * 2 + 1];
  }
  c0 = wave_sum(c0);
  c1 = wave_sum(c1);
  if (t == 0) {
    const float z0 = c0 + b2[0], z1 = c1 + b2[1];
    const float mz = fmaxf(z0, z1);
    const float lse = mz + logf(expf(z0 - mz) + expf(z1 - mz));
    out[row * 2 + 0] = z0 - lse;
    out[row * 2 + 1] = z1 - lse;
  }
}

// ---------------------------------------------------------------------------
extern "C" void kernel_launch(void* const* d_in, const int* in_sizes, int n_in,
                              void* d_out, int out_size, void* d_ws, size_t ws_size,
                              hipStream_t stream)
{
  if (n_in < 19) return;
  const float* x      = (const float*)d_in[0];
  const float* fc_w   = (const float*)d_in[1];
  const float* fc_b   = (const float*)d_in[2];
  const float* w_qkv  = (const float*)d_in[3];
  const float* b_qkv  = (const float*)d_in[4];
  const float* w_o    = (const float*)d_in[5];
  const float* b_o    = (const float*)d_in[6];
  const float* ln1_g  = (const float*)d_in[7];
  const float* ln1_b  = (const float*)d_in[8];
  const float* w_ff1  = (const float*)d_in[9];
  const float* b_ff1  = (const float*)d_in[10];
  const float* w_ff2  = (const float*)d_in[11];
  const float* b_ff2  = (const float*)d_in[12];
  const float* ln2_g  = (const float*)d_in[13];
  const float* ln2_b  = (const float*)d_in[14];
  const float* cls_w1 = (const float*)d_in[15];
  const float* cls_b1 = (const float*)d_in[16];
  const float* cls_w2 = (const float*)d_in[17];
  const float* cls_b2 = (const float*)d_in[18];
  float* out = (float*)d_out;

  // ---- workspace carve (~243 MB total) --------------------------------------
  char* wp = (char*)d_ws;
  auto alloc = [&](size_t bytes) -> char* {
    char* p = wp; wp += (bytes + 255) & ~(size_t)255; return p;
  };
  u16*   xb  = (u16*)  alloc((size_t)Bc * Tc * INc * 2);
  u16*   h0b = (u16*)  alloc((size_t)Bc * Tc * Dc * 2);
  u16*   qkv0= (u16*)  alloc((size_t)Bc * Tc * 3 * Dc * 2);
  u16*   vt0 = (u16*)  alloc((size_t)Dc * Bc * Tc * 2);      // [512][1024]
  // weights as contiguous 4-layer blocks
  u16* wtqA  = (u16*)alloc((size_t)Lc * 3 * Dc * Dc * 2);
  u16* wtoA  = (u16*)alloc((size_t)Lc * Dc * Dc * 2);
  u16* wtf1A = (u16*)alloc((size_t)Lc * Fc * Dc * 2);
  u16* wtf2A = (u16*)alloc((size_t)Lc * Dc * Fc * 2);
  u16* fcwt  = (u16*)alloc((size_t)Dc * INc * 2);            // [512][128]
  u16* w1t   = (u16*)alloc((size_t)256 * Dc * 2);            // [256][512]
  const size_t RS = (size_t)GMAXc + 64;   // slack rows for over-reads
  u16*   hb    = (u16*)  alloc((size_t)GMAXc * Dc * 2);
  u16*   qkvb  = (u16*)  alloc(RS * 3 * Dc * 2);   // also aliased as kv3 (L3)
  u16*   attno = (u16*)  alloc((size_t)GMAXc * Dc * 2);
  u16*   tmpb  = (u16*)  alloc((size_t)GMAXc * Dc * 2);
  u16*   ffb   = (u16*)  alloc((size_t)GMAXc * Fc * 2);
  u16*   vt    = (u16*)  alloc((size_t)Dc * VTSc * 2);
  u16*   hbdiag= (u16*)  alloc((size_t)DPADc * Dc * 2);
  u16*   attnd = (u16*)  alloc((size_t)DPADc * Dc * 2);
  u16*   qd    = (u16*)  alloc((size_t)DPADc * Dc * 2);
  u16*   ffc   = (u16*)  alloc((size_t)DALLc * 256 * 2);
  if ((size_t)(wp - (char*)d_ws) > ws_size) return;
  u16* kv3 = qkvb;   // L3 K/V buffer, stride 1024 (aliases qkvb)

  u16 *wtq[Lc], *wto[Lc], *wtf1[Lc], *wtf2[Lc];
  for (int l = 0; l < Lc; ++l) {
    wtq[l]  = wtqA  + (size_t)l * 3 * Dc * Dc;
    wto[l]  = wtoA  + (size_t)l * Dc * Dc;
    wtf1[l] = wtf1A + (size_t)l * Fc * Dc;
    wtf2[l] = wtf2A + (size_t)l * Dc * Fc;
  }

  // ---- weight transpose+convert (batched) -----------------------------------
  const dim3 tb(32, 8);
  transpose_conv4<<<dim3(3 * Dc / 32, Dc / 32, Lc), tb, 0, stream>>>(
      w_qkv, wtqA, Dc, 3 * Dc, (size_t)Dc * 3 * Dc, (size_t)3 * Dc * Dc);
  transpose_conv4<<<dim3(Dc / 32, Dc / 32, Lc), tb, 0, stream>>>(
      w_o, wtoA, Dc, Dc, (size_t)Dc * Dc, (size_t)Dc * Dc);
  transpose_conv4<<<dim3(Fc / 32, Dc / 32, Lc), tb, 0, stream>>>(
      w_ff1, wtf1A, Dc, Fc, (size_t)Dc * Fc, (size_t)Fc * Dc);
  transpose_conv4<<<dim3(Dc / 32, Fc / 32, Lc), tb, 0, stream>>>(
      w_ff2, wtf2A, Fc, Dc, (size_t)Fc * Dc, (size_t)Dc * Fc);
  transpose_conv4<<<dim3(Dc / 32, INc / 32, 1), tb, 0, stream>>>(
      fc_w, fcwt, INc, Dc, 0, 0);
  transpose_conv4<<<dim3(256 / 32, Dc / 32, 1), tb, 0, stream>>>(
      cls_w1, w1t, Dc, 256, 0, 0);

  // ---- fc: h0b = relu(xb @ fcwt^T + fc_b), bf16 MFMA ------------------------
  conv_bf16<<<(Bc * Tc * INc / 4 + 255) / 256, 256, 0, stream>>>(
      x, xb, Bc * Tc * INc);
  gemm_mfma_n64<true, true><<<dim3(Dc / 64, (Bc * Tc) / 128), 256, 0, stream>>>(
      xb, fcwt, fc_b, h0b, Bc * Tc, INc, Dc);

  // ---- layer-0 shared qkv (identical across prefixes) ----------------------
  gemm_mfma<false, true><<<dim3(3 * Dc / 128, (Bc * Tc) / 128), 256, 0, stream>>>(
      h0b, wtq[0], b_qkv, qkv0, Bc * Tc, Dc, 3 * Dc);
  transpose_v<<<dim3((Bc * Tc) / 64, 8), 256, 0, stream>>>(qkv0, vt0, Bc * Tc);

  for (int g = 0; g < NGc; ++g) {
    const int p0 = g_p0[g], np = g_np[g], gs = g_start[g], Mg = g_M[g];
    const int M3 = g_M3[g], doff = g_doff[g];

    // ---- layer 0 (shared qkv; bcast fused into res_ln0) --------------------
    attn_mfma_kernel<true><<<dim3(Hc, Bc, np), 64, 0, stream>>>(
        qkv0, vt0, Bc * Tc, attno, p0, gs);
    gemm_mfma_n64<false, true><<<dim3(Dc / 64, Mg / 128), 256, 0, stream>>>(
        attno, wto[0], b_o, tmpb, Mg, Dc, Dc);
    res_ln0_kernel<<<dim3(64, 16, np), 64, 0, stream>>>(
        h0b, hb, tmpb, ln1_g, ln1_b, p0, gs);
    gemm_mfma<true, true><<<dim3(Fc / 128, Mg / 128), 256, 0, stream>>>(
        hb, wtf1[0], b_ff1, ffb, Mg, Dc, Fc);
    gemm_mfma_n64<false, true><<<dim3(Dc / 64, Mg / 128), 256, 0, stream>>>(
        ffb, wtf2[0], b_ff2, tmpb, Mg, Fc, Dc);
    res_ln_kernel<<<Mg / 4, 256, 0, stream>>>(hb, tmpb, ln2_g, ln2_b);

    // ---- layers 1,2 --------------------------------------------------------
    for (int l = 1; l < 3; ++l) {
      gemm_mfma<false, true><<<dim3(3 * Dc / 128, Mg / 128), 256, 0, stream>>>(
          hb, wtq[l], b_qkv + (size_t)l * 3 * Dc, qkvb, Mg, Dc, 3 * Dc);
      transpose_v<<<dim3(Mg / 64, 8), 256, 0, stream>>>(qkvb, vt, VTSc);
      attn_mfma_kernel<false><<<dim3(Hc, Bc, np), 64, 0, stream>>>(
          qkvb, vt, VTSc, attno, p0, gs);
      gemm_mfma_n64<false, true><<<dim3(Dc / 64, Mg / 128), 256, 0, stream>>>(
          attno, wto[l], b_o + (size_t)l * Dc, tmpb, Mg, Dc, Dc);
      res_ln_kernel<<<Mg / 4, 256, 0, stream>>>(hb, tmpb, ln1_g + l * Dc, ln1_b + l * Dc);
      gemm_mfma<true, true><<<dim3(Fc / 128, Mg / 128), 256, 0, stream>>>(
          hb, wtf1[l], b_ff1 + (size_t)l * Fc, ffb, Mg, Dc, Fc);
      gemm_mfma_n64<false, true><<<dim3(Dc / 64, Mg / 128), 256, 0, stream>>>(
          ffb, wtf2[l], b_ff2 + (size_t)l * Dc, tmpb, Mg, Fc, Dc);
      res_ln_kernel<<<Mg / 4, 256, 0, stream>>>(hb, tmpb, ln2_g + l * Dc, ln2_b + l * Dc);
    }

    // ---- layer 3 (in-group part): diag gather, Q(diag), K/V(all), attn -----
    {
      const int l = 3;
      gather_diag<<<np * 16, 128, 0, stream>>>(hb, hbdiag, p0, gs, doff);
      gemm_mfma_n64<false, true><<<dim3(Dc / 64, M3 / 128), 256, 0, stream>>>(
          hbdiag + (size_t)doff * Dc, wtq[l], b_qkv + (size_t)l * 3 * Dc,
          qd + (size_t)doff * Dc, M3, Dc, Dc);
      gemm_mfma<false, true><<<dim3(2 * Dc / 128, Mg / 128), 256, 0, stream>>>(
          hb, wtq[l] + (size_t)512 * Dc, b_qkv + (size_t)l * 3 * Dc + 512,
          kv3, Mg, Dc, 2 * Dc);
      attn_diag_kernel<<<dim3(Hc, Bc, np), 64, 0, stream>>>(
          kv3, qd, attnd, p0, gs, doff);
    }
  }

  // ---- merged layer-3 tail on all 1024 diag rows ----------------------------
  {
    const int l = 3;
    gemm_mfma_n64<false, true><<<dim3(Dc / 64, DALLc / 128), 256, 0, stream>>>(
        attnd, wto[l], b_o + (size_t)l * Dc, tmpb, DALLc, Dc, Dc);
    res_ln_kernel<<<DALLc / 4, 256, 0, stream>>>(hbdiag, tmpb,
                                                 ln1_g + l * Dc, ln1_b + l * Dc);
    gemm_mfma<true, true><<<dim3(Fc / 128, DALLc / 128), 256, 0, stream>>>(
        hbdiag, wtf1[l], b_ff1 + (size_t)l * Fc, ffb, DALLc, Dc, Fc);
    gemm_mfma_n64<false, true><<<dim3(Dc / 64, DALLc / 128), 256, 0, stream>>>(
        ffb, wtf2[l], b_ff2 + (size_t)l * Dc, tmpb, DALLc, Fc, Dc);
    res_ln_kernel<<<DALLc / 4, 256, 0, stream>>>(hbdiag, tmpb,
                                                 ln2_g + l * Dc, ln2_b + l * Dc);
  }

  // ---- classifier: GEMM (relu) + 2-logit finisher ---------------------------
  gemm_mfma_n64<true, true><<<dim3(256 / 64, DALLc / 128), 256, 0, stream>>>(
      hbdiag, w1t, cls_b1, ffc, DALLc, Dc, 256);
  cls_fin_kernel<<<Bc * Tc, 64, 0, stream>>>(ffc, cls_w2, cls_b2, out);
}

// Round 20
// 1479.512 us; speedup vs baseline: 1.1018x; 1.1018x over previous
//
#include <hip/hip_runtime.h>
#include <math.h>

using u16 = unsigned short;
using u32 = unsigned int;

constexpr int Bc = 16;     // batch
constexpr int Tc = 64;     // tokens == prefixes
constexpr int INc = 128;
constexpr int Dc = 512;
constexpr int Hc = 8;
constexpr int Fc = 2048;
constexpr int Lc = 4;
constexpr float SCALEc = 0.125f;  // 1/sqrt(64)

// Compacted triangular layout with 8-aligned (p,b) segments. TWO groups.
constexpr int NGc = 2;
constexpr int g_p0[NGc]   = {0, 44};
constexpr int g_np[NGc]   = {44, 20};
constexpr int g_start[NGc]= {0, 18432};
constexpr int g_M[NGc]    = {18432, 18432};   // rows (%128==0, no padding)
constexpr int g_M3[NGc]   = {768, 384};       // per-group qd GEMM M (%128)
constexpr int g_doff[NGc] = {0, 704};         // diag row offsets (packed)
constexpr int GMAXc = 18432;
constexpr int DALLc = 1024;          // total diag rows (704+320)
constexpr int DPADc = 1152;          // diag buffers incl. qd-GEMM overrun
constexpr int VTSc  = GMAXc + 64;    // vt row stride (slack for over-read)

typedef __attribute__((ext_vector_type(8))) short bf16x8;
typedef __attribute__((ext_vector_type(4))) float f32x4;

__device__ __forceinline__ int rowbase(int p) {  // C(p)
  const int q = p >> 3, r = p & 7;
  return 128 * (4 * q * (q + 1) + r * (q + 1));
}

__device__ __forceinline__ float bf2f(u16 u) {
  union { u32 i; float f; } c; c.i = (u32)u << 16; return c.f;
}
__device__ __forceinline__ u16 f2bf(float f) {
  union { float f; u32 u; } c{f};
  u32 r = (c.u + 0x7fffu + ((c.u >> 16) & 1u)) >> 16;
  return (u16)r;
}

// ---------------------------------------------------------------------------
// fp32 -> bf16 convert (x input)
// ---------------------------------------------------------------------------
__global__ __launch_bounds__(256) void conv_bf16(
    const float* __restrict__ x, u16* __restrict__ xb, int n)
{
  const int i = (blockIdx.x * 256 + threadIdx.x) * 4;
  if (i < n) {
    const float4 v = *(const float4*)(x + i);
    uint2 pk;
    pk.x = (u32)f2bf(v.x) | ((u32)f2bf(v.y) << 16);
    pk.y = (u32)f2bf(v.z) | ((u32)f2bf(v.w) << 16);
    *(uint2*)(xb + i) = pk;
  }
}

// ---------------------------------------------------------------------------
// Weight convert+transpose, multi-layer (grid.z = layer):
// src fp32 [K][N] -> dst bf16 [N][K], per-layer strides.
// ---------------------------------------------------------------------------
__global__ __launch_bounds__(256) void transpose_conv4(
    const float* __restrict__ src0, u16* __restrict__ dst0, int K, int N,
    size_t sstride, size_t dstride)
{
  const float* src = src0 + (size_t)blockIdx.z * sstride;
  u16* dst = dst0 + (size_t)blockIdx.z * dstride;
  __shared__ float t[32][33];
  const int bx = blockIdx.x * 32;
  const int by = blockIdx.y * 32;
  const int x = threadIdx.x, y = threadIdx.y;  // 32 x 8
#pragma unroll
  for (int i = 0; i < 32; i += 8) t[y + i][x] = src[(size_t)(by + y + i) * N + bx + x];
  __syncthreads();
#pragma unroll
  for (int i = 0; i < 32; i += 8)
    dst[(size_t)(bx + y + i) * K + by + x] = f2bf(t[x][y + i]);
}

// ---------------------------------------------------------------------------
// V transpose: qkvsrc[r][1024+d] (stride 1536) -> vt[d][r], 64x64 LDS tiles.
// ---------------------------------------------------------------------------
__global__ __launch_bounds__(256) void transpose_v(
    const u16* __restrict__ qkvsrc, u16* __restrict__ vt, int vstride)
{
  __shared__ u16 t[64][65];
  const int r0 = blockIdx.x * 64;
  const int d0 = blockIdx.y * 64;
  const int tid = threadIdx.x;
  const int rr = tid >> 2, cc = (tid & 3) * 16;
  const u16* src = qkvsrc + (size_t)(r0 + rr) * 1536 + 1024 + d0 + cc;
  union { uint4 v; u16 s[8]; } ua, ub;
  ua.v = *(const uint4*)src;
  ub.v = *(const uint4*)(src + 8);
#pragma unroll
  for (int i = 0; i < 8; ++i) { t[rr][cc + i] = ua.s[i]; t[rr][cc + 8 + i] = ub.s[i]; }
  __syncthreads();
  const int dd = tid >> 2, kk = (tid & 3) * 16;
  union { uint4 v; u16 s[8]; } w0, w1;
#pragma unroll
  for (int i = 0; i < 8; ++i) { w0.s[i] = t[kk + i][dd]; w1.s[i] = t[kk + 8 + i][dd]; }
  u16* dst = vt + (size_t)(d0 + dd) * vstride + r0 + kk;
  *(uint4*)dst = w0.v;
  *(uint4*)(dst + 8) = w1.v;
}

// ---------------------------------------------------------------------------
// LDS staging helpers (pre-swizzled SOURCE, linear dest).
// ---------------------------------------------------------------------------
__device__ __forceinline__ void stage_tile(const u16* __restrict__ src, int ldk, u16* lds)
{
  const int tid = threadIdx.x;
#pragma unroll
  for (int q = 0; q < 4; ++q) {
    const int p16 = tid + (q << 8);
    const int row = p16 >> 3;
    const int s   = p16 & 7;
    const int k16 = s ^ (row & 7);
    const u16* g = src + (size_t)row * ldk + (k16 << 3);
    __builtin_amdgcn_global_load_lds(
        (const __attribute__((address_space(1))) void*)g,
        (__attribute__((address_space(3))) void*)(lds + (p16 << 3)),
        16, 0, 0);
  }
}

__device__ __forceinline__ void stage_tile64(const u16* __restrict__ src, int ldk, u16* lds)
{
  const int tid = threadIdx.x;
#pragma unroll
  for (int q = 0; q < 2; ++q) {
    const int p16 = tid + (q << 8);      // 512 granules: 64 rows x 8
    const int row = p16 >> 3;
    const int s   = p16 & 7;
    const int k16 = s ^ (row & 7);
    const u16* g = src + (size_t)row * ldk + (k16 << 3);
    __builtin_amdgcn_global_load_lds(
        (const __attribute__((address_space(1))) void*)g,
        (__attribute__((address_space(3))) void*)(lds + (p16 << 3)),
        16, 0, 0);
  }
}

// ---------------------------------------------------------------------------
// bf16 MFMA GEMM: 128x128 tile, BK=64, dbuf, counted vmcnt(8).
// Used for the wide-N GEMMs (qkv N=1536, ff1 N=2048, kv3 N=1024).
// ---------------------------------------------------------------------------
template<bool RELU, bool OUT_BF16>
__global__ __launch_bounds__(256) void gemm_mfma(
    const u16* __restrict__ A, const u16* __restrict__ Wt,
    const float* __restrict__ bias, void* __restrict__ Cout,
    int M, int K, int N)
{
  __shared__ u16 As[2][128 * 64];
  __shared__ u16 Bs[2][128 * 64];

  const int tid  = threadIdx.x;
  const int lane = tid & 63;
  const int wave = tid >> 6;
  const int wr = wave >> 1;
  const int wc = wave & 1;

  const int gx = gridDim.x;
  const int nwg = gx * gridDim.y;
  const int lin = blockIdx.y * gx + blockIdx.x;
  const int qq = nwg >> 3, r8 = nwg & 7;
  const int xcd = lin & 7, pos = lin >> 3;
  const int orig = (xcd < r8) ? (xcd * (qq + 1) + pos)
                              : (r8 * (qq + 1) + (xcd - r8) * qq + pos);
  const int row0 = (orig / gx) * 128;
  const int col0 = (orig % gx) * 128;

  f32x4 acc[4][4];
#pragma unroll
  for (int i = 0; i < 4; ++i)
#pragma unroll
    for (int j = 0; j < 4; ++j) acc[i][j] = f32x4{0.f, 0.f, 0.f, 0.f};

  const int nk = K >> 6;
  const int arow = wr * 64 + (lane & 15);
  const int brow = wc * 64 + (lane & 15);
  const int kq   = lane >> 4;

  stage_tile(A  + (size_t)row0 * K, K, &As[0][0]);
  stage_tile(Wt + (size_t)col0 * K, K, &Bs[0][0]);

  for (int t = 0; t < nk; ++t) {
    const int cur = t & 1;
    if (t + 1 < nk) {
      const int k0 = (t + 1) << 6;
      stage_tile(A  + (size_t)row0 * K + k0, K, &As[cur ^ 1][0]);
      stage_tile(Wt + (size_t)col0 * K + k0, K, &Bs[cur ^ 1][0]);
      asm volatile("s_waitcnt vmcnt(8)\n\ts_barrier" ::: "memory");
    } else {
      asm volatile("s_waitcnt vmcnt(0)\n\ts_barrier" ::: "memory");
    }
    const u16* Ab = &As[cur][0];
    const u16* Bb = &Bs[cur][0];
#pragma unroll
    for (int kk = 0; kk < 2; ++kk) {
      bf16x8 af[4], bfr[4];
      const int c = kk * 4 + kq;
#pragma unroll
      for (int i = 0; i < 4; ++i) {
        const int ra = arow + i * 16;
        af[i]  = *reinterpret_cast<const bf16x8*>(Ab + ra * 64 + ((c ^ (ra & 7)) << 3));
        const int rb = brow + i * 16;
        bfr[i] = *reinterpret_cast<const bf16x8*>(Bb + rb * 64 + ((c ^ (rb & 7)) << 3));
      }
#pragma unroll
      for (int mi = 0; mi < 4; ++mi)
#pragma unroll
        for (int ni = 0; ni < 4; ++ni)
          acc[mi][ni] = __builtin_amdgcn_mfma_f32_16x16x32_bf16(af[mi], bfr[ni], acc[mi][ni], 0, 0, 0);
    }
    asm volatile("s_barrier" ::: "memory");
  }

  const int r0 = row0 + wr * 64 + ((lane >> 4) << 2);
  const int c0 = col0 + wc * 64 + (lane & 15);
#pragma unroll
  for (int mi = 0; mi < 4; ++mi)
#pragma unroll
    for (int ni = 0; ni < 4; ++ni) {
      const int col = c0 + ni * 16;
      const float bsv = bias[col];
#pragma unroll
      for (int j = 0; j < 4; ++j) {
        const int row = r0 + mi * 16 + j;
        float o = acc[mi][ni][j] + bsv;
        if (RELU) o = fmaxf(o, 0.f);
        if (OUT_BF16) ((u16*)Cout)[(size_t)row * N + col] = f2bf(o);
        else          ((float*)Cout)[(size_t)row * N + col] = o;
      }
    }
}

// ---------------------------------------------------------------------------
// Narrow-N GEMM (round-16 proven): 128x64 tile, BK=64, dbuf, counted
// vmcnt(6), two fused barriers per step. 48 KB LDS -> 3 blocks/CU.
// Used for N=512/256-class GEMMs (o-proj/ff2/qd/tail/fc/cls).
// ---------------------------------------------------------------------------
template<bool RELU, bool OUT_BF16>
__global__ __launch_bounds__(256) void gemm_mfma_n64(
    const u16* __restrict__ A, const u16* __restrict__ Wt,
    const float* __restrict__ bias, void* __restrict__ Cout,
    int M, int K, int N)
{
  __shared__ u16 As[2][128 * 64];
  __shared__ u16 Bs[2][64 * 64];

  const int tid  = threadIdx.x;
  const int lane = tid & 63;
  const int wave = tid >> 6;        // 0..3, each owns 32 rows x 64 cols

  const int gx = gridDim.x;
  const int nwg = gx * gridDim.y;
  const int lin = blockIdx.y * gx + blockIdx.x;
  const int qq = nwg >> 3, r8 = nwg & 7;
  const int xcd = lin & 7, pos = lin >> 3;
  const int orig = (xcd < r8) ? (xcd * (qq + 1) + pos)
                              : (r8 * (qq + 1) + (xcd - r8) * qq + pos);
  const int row0 = (orig / gx) * 128;
  const int col0 = (orig % gx) * 64;

  f32x4 acc[2][4];
#pragma unroll
  for (int i = 0; i < 2; ++i)
#pragma unroll
    for (int j = 0; j < 4; ++j) acc[i][j] = f32x4{0.f, 0.f, 0.f, 0.f};

  const int nk = K >> 6;
  const int arow = wave * 32 + (lane & 15);
  const int brow = lane & 15;
  const int kq   = lane >> 4;

  stage_tile  (A  + (size_t)row0 * K, K, &As[0][0]);
  stage_tile64(Wt + (size_t)col0 * K, K, &Bs[0][0]);

  for (int t = 0; t < nk; ++t) {
    const int cur = t & 1;
    if (t + 1 < nk) {
      const int k0 = (t + 1) << 6;
      stage_tile  (A  + (size_t)row0 * K + k0, K, &As[cur ^ 1][0]);
      stage_tile64(Wt + (size_t)col0 * K + k0, K, &Bs[cur ^ 1][0]);
      asm volatile("s_waitcnt vmcnt(6)\n\ts_barrier" ::: "memory");
    } else {
      asm volatile("s_waitcnt vmcnt(0)\n\ts_barrier" ::: "memory");
    }
    const u16* Ab = &As[cur][0];
    const u16* Bb = &Bs[cur][0];
#pragma unroll
    for (int kk = 0; kk < 2; ++kk) {
      bf16x8 af[2], bfr[4];
      const int c = kk * 4 + kq;
#pragma unroll
      for (int i = 0; i < 2; ++i) {
        const int ra = arow + i * 16;
        af[i] = *reinterpret_cast<const bf16x8*>(Ab + ra * 64 + ((c ^ (ra & 7)) << 3));
      }
#pragma unroll
      for (int i = 0; i < 4; ++i) {
        const int rb = brow + i * 16;
        bfr[i] = *reinterpret_cast<const bf16x8*>(Bb + rb * 64 + ((c ^ (rb & 7)) << 3));
      }
#pragma unroll
      for (int mi = 0; mi < 2; ++mi)
#pragma unroll
        for (int ni = 0; ni < 4; ++ni)
          acc[mi][ni] = __builtin_amdgcn_mfma_f32_16x16x32_bf16(af[mi], bfr[ni], acc[mi][ni], 0, 0, 0);
    }
    asm volatile("s_barrier" ::: "memory");
  }

  const int r0 = row0 + wave * 32 + ((lane >> 4) << 2);
  const int c0 = col0 + (lane & 15);
#pragma unroll
  for (int mi = 0; mi < 2; ++mi)
#pragma unroll
    for (int ni = 0; ni < 4; ++ni) {
      const int col = c0 + ni * 16;
      const float bsv = bias[col];
#pragma unroll
      for (int j = 0; j < 4; ++j) {
        const int row = r0 + mi * 16 + j;
        float o = acc[mi][ni][j] + bsv;
        if (RELU) o = fmaxf(o, 0.f);
        if (OUT_BF16) ((u16*)Cout)[(size_t)row * N + col] = f2bf(o);
        else          ((float*)Cout)[(size_t)row * N + col] = o;
      }
    }
}

// ---------------------------------------------------------------------------
// MFMA flash attention. One 64-lane wave per (head, b, p).
// ---------------------------------------------------------------------------
template<bool SHARED>
__global__ __launch_bounds__(64) void attn_mfma_kernel(
    const u16* __restrict__ qkv, const u16* __restrict__ vt, int vstride,
    u16* __restrict__ attno, int p0, int gstart)
{
  const int hh = blockIdx.x, b = blockIdx.y, p = p0 + blockIdx.z;
  const int NT = p + 1;
  const int NT8 = (NT + 7) & ~7;
  const int rb = rowbase(p) + b * NT8 - gstart;   // output row base
  const int sb = SHARED ? (b * 64) : rb;          // source row base
  const int tid = threadIdx.x;
  const int lc = tid & 15, lg = tid >> 4;

  __shared__ u16 Plds[64][72];     // P[q][k]
  __shared__ u16 VTl[4096];        // V^T [d][k], 16B-granule swizzled
  __shared__ float invl[64];

  {
    const u16* vbase = vt + (size_t)(hh * 64) * vstride + sb;
#pragma unroll
    for (int it = 0; it < 8; ++it) {
      const int gi = tid + (it << 6);
      const int dd = gi >> 3, s = gi & 7;
      const u16* src = vbase + (size_t)dd * vstride + ((s ^ (dd & 7)) << 3);
      __builtin_amdgcn_global_load_lds(
          (const __attribute__((address_space(1))) void*)src,
          (__attribute__((address_space(3))) void*)(&VTl[gi << 3]), 16, 0, 0);
    }
  }

  f32x4 st[4][4];
#pragma unroll
  for (int i = 0; i < 4; ++i)
#pragma unroll
    for (int j = 0; j < 4; ++j) st[i][j] = f32x4{0.f, 0.f, 0.f, 0.f};

#pragma unroll
  for (int kt = 0; kt < 2; ++kt) {
    bf16x8 kf[4], qf[4];
#pragma unroll
    for (int t = 0; t < 4; ++t) {
      if (t * 16 < NT) {
        const size_t rbase = (size_t)(sb + t * 16 + lc) * 1536 + hh * 64 + kt * 32 + lg * 8;
        qf[t] = *reinterpret_cast<const bf16x8*>(qkv + rbase);
        kf[t] = *reinterpret_cast<const bf16x8*>(qkv + rbase + 512);
      }
    }
#pragma unroll
    for (int mi = 0; mi < 4; ++mi)
      if (mi * 16 < NT)
#pragma unroll
        for (int ni = 0; ni < 4; ++ni)
          if (ni * 16 < NT)
            st[mi][ni] = __builtin_amdgcn_mfma_f32_16x16x32_bf16(kf[mi], qf[ni], st[mi][ni], 0, 0, 0);
  }

#pragma unroll
  for (int ni = 0; ni < 4; ++ni) {
    float mm = -3.0e38f;
#pragma unroll
    for (int mi = 0; mi < 4; ++mi)
#pragma unroll
      for (int e = 0; e < 4; ++e)
        if (16 * mi + 4 * lg + e < NT) mm = fmaxf(mm, st[mi][ni][e]);
    mm = fmaxf(mm, __shfl_xor(mm, 16));
    mm = fmaxf(mm, __shfl_xor(mm, 32));
    float ss = 0.f;
#pragma unroll
    for (int mi = 0; mi < 4; ++mi) {
      u16 pb[4];
#pragma unroll
      for (int e = 0; e < 4; ++e) {
        const float pe = (16 * mi + 4 * lg + e < NT)
                           ? __expf((st[mi][ni][e] - mm) * SCALEc) : 0.f;
        ss += pe;
        pb[e] = f2bf(pe);
      }
      uint2 pk;
      pk.x = (u32)pb[0] | ((u32)pb[1] << 16);
      pk.y = (u32)pb[2] | ((u32)pb[3] << 16);
      *reinterpret_cast<uint2*>(&Plds[16 * ni + lc][16 * mi + 4 * lg]) = pk;
    }
    ss += __shfl_xor(ss, 16);
    ss += __shfl_xor(ss, 32);
    if (lg == 0) invl[16 * ni + lc] = 1.f / ss;
  }

  asm volatile("s_waitcnt vmcnt(0)" ::: "memory");
  __syncthreads();

  f32x4 oc[4][4];
#pragma unroll
  for (int i = 0; i < 4; ++i)
#pragma unroll
    for (int j = 0; j < 4; ++j) oc[i][j] = f32x4{0.f, 0.f, 0.f, 0.f};

#pragma unroll
  for (int kt = 0; kt < 2; ++kt) {
    if (kt * 32 < NT) {
      bf16x8 pa[4], vbf[4];
#pragma unroll
      for (int t = 0; t < 4; ++t) {
        if (t * 16 < NT)
          pa[t] = *reinterpret_cast<const bf16x8*>(&Plds[t * 16 + lc][kt * 32 + lg * 8]);
        const int dd = t * 16 + lc;
        vbf[t] = *reinterpret_cast<const bf16x8*>(
            &VTl[dd * 64 + (((4 * kt + lg) ^ (lc & 7)) << 3)]);
      }
#pragma unroll
      for (int qt = 0; qt < 4; ++qt)
        if (qt * 16 < NT)
#pragma unroll
          for (int dt = 0; dt < 4; ++dt)
            oc[qt][dt] = __builtin_amdgcn_mfma_f32_16x16x32_bf16(pa[qt], vbf[dt], oc[qt][dt], 0, 0, 0);
    }
  }

#pragma unroll
  for (int qt = 0; qt < 4; ++qt) {
    if (qt * 16 < NT) {
#pragma unroll
      for (int e = 0; e < 4; ++e) {
        const int qrow = qt * 16 + 4 * lg + e;
        if (qrow < NT) {
          const float inv = invl[qrow];
          u16* dst = attno + (size_t)(rb + qrow) * Dc + hh * 64 + lc;
#pragma unroll
          for (int dt = 0; dt < 4; ++dt)
            dst[dt * 16] = f2bf(oc[qt][dt][e] * inv);
        }
      }
    }
  }
}

// ---------------------------------------------------------------------------
// Layer-3 attention: diagonal query only.
// ---------------------------------------------------------------------------
__global__ __launch_bounds__(64) void attn_diag_kernel(
    const u16* __restrict__ kv3, const u16* __restrict__ qd,
    u16* __restrict__ attno_d, int p0, int gstart, int doff)
{
  const int hh = blockIdx.x, b = blockIdx.y, pl = blockIdx.z;
  const int p = p0 + pl;
  const int NT = p + 1;
  const int NT8 = (NT + 7) & ~7;
  const int rb = rowbase(p) + b * NT8 - gstart;
  const int tid = threadIdx.x;
  const int rd = doff + pl * 16 + b;

  __shared__ u16 Ks[64][64];
  __shared__ u16 Vs[64][64];

  const int lrow = tid >> 3;
  const int lc8  = tid & 7;
  for (int t0 = 0; t0 < NT; t0 += 8) {
    const int tr = rb + t0 + lrow;
    const int csrc = (lc8 ^ lrow) << 3;
    const u16* gk = kv3 + (size_t)tr * 1024 + hh * 64 + csrc;
    const u16* gv = kv3 + (size_t)tr * 1024 + 512 + hh * 64 + csrc;
    __builtin_amdgcn_global_load_lds(
        (const __attribute__((address_space(1))) void*)gk,
        (__attribute__((address_space(3))) void*)(&Ks[t0][0] + tid * 8), 16, 0, 0);
    __builtin_amdgcn_global_load_lds(
        (const __attribute__((address_space(1))) void*)gv,
        (__attribute__((address_space(3))) void*)(&Vs[t0][0] + tid * 8), 16, 0, 0);
  }

  const u16* qp = qd + (size_t)rd * Dc + hh * 64;
  float qv[64];
#pragma unroll
  for (int c8 = 0; c8 < 8; ++c8) {
    const bf16x8 q8 = *reinterpret_cast<const bf16x8*>(qp + c8 * 8);
#pragma unroll
    for (int i = 0; i < 8; ++i) qv[c8 * 8 + i] = bf2f((u16)q8[i]);
  }
  asm volatile("s_waitcnt vmcnt(0)" ::: "memory");
  __syncthreads();

  float dot = -1e30f;
  if (tid < NT) {
    dot = 0.f;
#pragma unroll
    for (int c8 = 0; c8 < 8; ++c8) {
      const bf16x8 k8 = *reinterpret_cast<const bf16x8*>(
          &Ks[tid][0] + ((c8 ^ (tid & 7)) << 3));
#pragma unroll
      for (int i = 0; i < 8; ++i) dot += qv[c8 * 8 + i] * bf2f((u16)k8[i]);
    }
    dot *= SCALEc;
  }
  float mm = dot;
#pragma unroll
  for (int off = 32; off; off >>= 1) mm = fmaxf(mm, __shfl_xor(mm, off));
  const float pt = __expf(dot - mm);
  float s = pt;
#pragma unroll
  for (int off = 32; off; off >>= 1) s += __shfl_xor(s, off);
  const float inv = 1.f / s;

  float o = 0.f;   // lane owns output dim d = tid
  for (int t = 0; t < NT; ++t) {
    const float ptt = __shfl(pt, t);
    o += ptt * bf2f(Vs[t][(((tid >> 3) ^ (t & 7)) << 3) + (tid & 7)]);
  }
  attno_d[(size_t)rd * Dc + hh * 64 + tid] = f2bf(o * inv);
}

// ---------------------------------------------------------------------------
// hb = LN(hb + tmpb), bf16 residual carrier. 4 rows/block.
// ---------------------------------------------------------------------------
__device__ inline float wave_sum(float v) {
#pragma unroll
  for (int off = 32; off; off >>= 1) v += __shfl_xor(v, off);
  return v;
}

__global__ __launch_bounds__(256) void res_ln_kernel(
    u16* __restrict__ hb, const u16* __restrict__ tmpb,
    const float* __restrict__ g, const float* __restrict__ bt)
{
  const size_t row = (size_t)blockIdx.x * 4 + (threadIdx.x >> 6);
  const int t = threadIdx.x & 63;
  float v[8];
  float s = 0.f;
#pragma unroll
  for (int i = 0; i < 8; ++i) {
    v[i] = bf2f(hb[row * Dc + i * 64 + t]) + bf2f(tmpb[row * Dc + i * 64 + t]);
    s += v[i];
  }
  s = wave_sum(s);
  const float mean = s * (1.f / 512.f);
  float vs = 0.f;
#pragma unroll
  for (int i = 0; i < 8; ++i) { const float d = v[i] - mean; vs += d * d; }
  vs = wave_sum(vs);
  const float rstd = rsqrtf(vs * (1.f / 512.f) + 1e-5f);
#pragma unroll
  for (int i = 0; i < 8; ++i)
    hb[row * Dc + i * 64 + t] =
        f2bf((v[i] - mean) * rstd * g[i * 64 + t] + bt[i * 64 + t]);
}

// ---------------------------------------------------------------------------
// Fused broadcast + layer-0 LN1: hb = LN(h0b[b,t] + tmpb[row]).
// ---------------------------------------------------------------------------
__global__ __launch_bounds__(64) void res_ln0_kernel(
    const u16* __restrict__ h0b, u16* __restrict__ hb,
    const u16* __restrict__ tmpb, const float* __restrict__ g,
    const float* __restrict__ bt, int p0, int gstart)
{
  const int t = blockIdx.x, b = blockIdx.y, p = p0 + blockIdx.z;
  if (t > p) return;
  const int NT8 = (p + 8) & ~7;
  const size_t row = (size_t)(rowbase(p) + b * NT8 + t - gstart);
  const int tt = threadIdx.x;
  const u16* src = h0b + (size_t)(b * 64 + t) * Dc;
  float v[8];
  float s = 0.f;
#pragma unroll
  for (int i = 0; i < 8; ++i) {
    v[i] = bf2f(src[i * 64 + tt]) + bf2f(tmpb[row * Dc + i * 64 + tt]);
    s += v[i];
  }
  s = wave_sum(s);
  const float mean = s * (1.f / 512.f);
  float vs = 0.f;
#pragma unroll
  for (int i = 0; i < 8; ++i) { const float d = v[i] - mean; vs += d * d; }
  vs = wave_sum(vs);
  const float rstd = rsqrtf(vs * (1.f / 512.f) + 1e-5f);
#pragma unroll
  for (int i = 0; i < 8; ++i)
    hb[row * Dc + i * 64 + tt] =
        f2bf((v[i] - mean) * rstd * g[i * 64 + tt] + bt[i * 64 + tt]);
}

// ---------------------------------------------------------------------------
// Diag gather (bf16 copy)
// ---------------------------------------------------------------------------
__global__ __launch_bounds__(128) void gather_diag(
    const u16* __restrict__ hb, u16* __restrict__ hbd,
    int p0, int gstart, int doff)
{
  const int pl = blockIdx.x >> 4, b = blockIdx.x & 15;
  const int p = p0 + pl;
  const int NT8 = (p + 8) & ~7;
  const size_t src = (size_t)(rowbase(p) + b * NT8 + p - gstart);
  ((uint2*)(hbd + (size_t)(doff + blockIdx.x) * Dc))[threadIdx.x] =
      ((const uint2*)(hb + src * Dc))[threadIdx.x];
}

// ---------------------------------------------------------------------------
// Classifier finish: 2-logit GEMV on ffc (bf16) + log_softmax.
// ---------------------------------------------------------------------------
__global__ __launch_bounds__(64) void cls_fin_kernel(
    const u16* __restrict__ ffc, const float* __restrict__ w2,
    const float* __restrict__ b2, float* __restrict__ out)
{
  const int row = blockIdx.x;
  const int b = row >> 6, p = row & 63;
  const int rd = (p < 44) ? (p * 16 + b) : (704 + (p - 44) * 16 + b);
  const int t = threadIdx.x;
  float c0 = 0.f, c1 = 0.f;
#pragma unroll
  for (int k = 0; k < 4; ++k) {
    const int j = t + k * 64;
    const float fv = bf2f(ffc[(size_t)rd * 256 + j]);
    c0 += fv * w2[j * 2 + 0];
    c1 += fv * w2[j * 2 + 1];
  }
  c0 = wave_sum(c0);
  c1 = wave_sum(c1);
  if (t == 0) {
    const float z0 = c0 + b2[0], z1 = c1 + b2[1];
    const float mz = fmaxf(z0, z1);
    const float lse = mz + logf(expf(z0 - mz) + expf(z1 - mz));
    out[row * 2 + 0] = z0 - lse;
    out[row * 2 + 1] = z1 - lse;
  }
}

// ---------------------------------------------------------------------------
extern "C" void kernel_launch(void* const* d_in, const int* in_sizes, int n_in,
                              void* d_out, int out_size, void* d_ws, size_t ws_size,
                              hipStream_t stream)
{
  if (n_in < 19) return;
  const float* x      = (const float*)d_in[0];
  const float* fc_w   = (const float*)d_in[1];
  const float* fc_b   = (const float*)d_in[2];
  const float* w_qkv  = (const float*)d_in[3];
  const float* b_qkv  = (const float*)d_in[4];
  const float* w_o    = (const float*)d_in[5];
  const float* b_o    = (const float*)d_in[6];
  const float* ln1_g  = (const float*)d_in[7];
  const float* ln1_b  = (const float*)d_in[8];
  const float* w_ff1  = (const float*)d_in[9];
  const float* b_ff1  = (const float*)d_in[10];
  const float* w_ff2  = (const float*)d_in[11];
  const float* b_ff2  = (const float*)d_in[12];
  const float* ln2_g  = (const float*)d_in[13];
  const float* ln2_b  = (const float*)d_in[14];
  const float* cls_w1 = (const float*)d_in[15];
  const float* cls_b1 = (const float*)d_in[16];
  const float* cls_w2 = (const float*)d_in[17];
  const float* cls_b2 = (const float*)d_in[18];
  float* out = (float*)d_out;

  // ---- workspace carve (~243 MB total) --------------------------------------
  char* wp = (char*)d_ws;
  auto alloc = [&](size_t bytes) -> char* {
    char* p = wp; wp += (bytes + 255) & ~(size_t)255; return p;
  };
  u16*   xb  = (u16*)  alloc((size_t)Bc * Tc * INc * 2);
  u16*   h0b = (u16*)  alloc((size_t)Bc * Tc * Dc * 2);
  u16*   qkv0= (u16*)  alloc((size_t)Bc * Tc * 3 * Dc * 2);
  u16*   vt0 = (u16*)  alloc((size_t)Dc * Bc * Tc * 2);      // [512][1024]
  // weights as contiguous 4-layer blocks
  u16* wtqA  = (u16*)alloc((size_t)Lc * 3 * Dc * Dc * 2);
  u16* wtoA  = (u16*)alloc((size_t)Lc * Dc * Dc * 2);
  u16* wtf1A = (u16*)alloc((size_t)Lc * Fc * Dc * 2);
  u16* wtf2A = (u16*)alloc((size_t)Lc * Dc * Fc * 2);
  u16* fcwt  = (u16*)alloc((size_t)Dc * INc * 2);            // [512][128]
  u16* w1t   = (u16*)alloc((size_t)256 * Dc * 2);            // [256][512]
  const size_t RS = (size_t)GMAXc + 64;   // slack rows for over-reads
  u16*   hb    = (u16*)  alloc((size_t)GMAXc * Dc * 2);
  u16*   qkvb  = (u16*)  alloc(RS * 3 * Dc * 2);   // also aliased as kv3 (L3)
  u16*   attno = (u16*)  alloc((size_t)GMAXc * Dc * 2);
  u16*   tmpb  = (u16*)  alloc((size_t)GMAXc * Dc * 2);
  u16*   ffb   = (u16*)  alloc((size_t)GMAXc * Fc * 2);
  u16*   vt    = (u16*)  alloc((size_t)Dc * VTSc * 2);
  u16*   hbdiag= (u16*)  alloc((size_t)DPADc * Dc * 2);
  u16*   attnd = (u16*)  alloc((size_t)DPADc * Dc * 2);
  u16*   qd    = (u16*)  alloc((size_t)DPADc * Dc * 2);
  u16*   ffc   = (u16*)  alloc((size_t)DALLc * 256 * 2);
  if ((size_t)(wp - (char*)d_ws) > ws_size) return;
  u16* kv3 = qkvb;   // L3 K/V buffer, stride 1024 (aliases qkvb)

  u16 *wtq[Lc], *wto[Lc], *wtf1[Lc], *wtf2[Lc];
  for (int l = 0; l < Lc; ++l) {
    wtq[l]  = wtqA  + (size_t)l * 3 * Dc * Dc;
    wto[l]  = wtoA  + (size_t)l * Dc * Dc;
    wtf1[l] = wtf1A + (size_t)l * Fc * Dc;
    wtf2[l] = wtf2A + (size_t)l * Dc * Fc;
  }

  // ---- weight transpose+convert (batched) -----------------------------------
  const dim3 tb(32, 8);
  transpose_conv4<<<dim3(3 * Dc / 32, Dc / 32, Lc), tb, 0, stream>>>(
      w_qkv, wtqA, Dc, 3 * Dc, (size_t)Dc * 3 * Dc, (size_t)3 * Dc * Dc);
  transpose_conv4<<<dim3(Dc / 32, Dc / 32, Lc), tb, 0, stream>>>(
      w_o, wtoA, Dc, Dc, (size_t)Dc * Dc, (size_t)Dc * Dc);
  transpose_conv4<<<dim3(Fc / 32, Dc / 32, Lc), tb, 0, stream>>>(
      w_ff1, wtf1A, Dc, Fc, (size_t)Dc * Fc, (size_t)Fc * Dc);
  transpose_conv4<<<dim3(Dc / 32, Fc / 32, Lc), tb, 0, stream>>>(
      w_ff2, wtf2A, Fc, Dc, (size_t)Fc * Dc, (size_t)Dc * Fc);
  transpose_conv4<<<dim3(Dc / 32, INc / 32, 1), tb, 0, stream>>>(
      fc_w, fcwt, INc, Dc, 0, 0);
  transpose_conv4<<<dim3(256 / 32, Dc / 32, 1), tb, 0, stream>>>(
      cls_w1, w1t, Dc, 256, 0, 0);

  // ---- fc: h0b = relu(xb @ fcwt^T + fc_b), bf16 MFMA ------------------------
  conv_bf16<<<(Bc * Tc * INc / 4 + 255) / 256, 256, 0, stream>>>(
      x, xb, Bc * Tc * INc);
  gemm_mfma_n64<true, true><<<dim3(Dc / 64, (Bc * Tc) / 128), 256, 0, stream>>>(
      xb, fcwt, fc_b, h0b, Bc * Tc, INc, Dc);

  // ---- layer-0 shared qkv (identical across prefixes) ----------------------
  gemm_mfma<false, true><<<dim3(3 * Dc / 128, (Bc * Tc) / 128), 256, 0, stream>>>(
      h0b, wtq[0], b_qkv, qkv0, Bc * Tc, Dc, 3 * Dc);
  transpose_v<<<dim3((Bc * Tc) / 64, 8), 256, 0, stream>>>(qkv0, vt0, Bc * Tc);

  for (int g = 0; g < NGc; ++g) {
    const int p0 = g_p0[g], np = g_np[g], gs = g_start[g], Mg = g_M[g];
    const int M3 = g_M3[g], doff = g_doff[g];

    // ---- layer 0 (shared qkv; bcast fused into res_ln0) --------------------
    attn_mfma_kernel<true><<<dim3(Hc, Bc, np), 64, 0, stream>>>(
        qkv0, vt0, Bc * Tc, attno, p0, gs);
    gemm_mfma_n64<false, true><<<dim3(Dc / 64, Mg / 128), 256, 0, stream>>>(
        attno, wto[0], b_o, tmpb, Mg, Dc, Dc);
    res_ln0_kernel<<<dim3(64, 16, np), 64, 0, stream>>>(
        h0b, hb, tmpb, ln1_g, ln1_b, p0, gs);
    gemm_mfma<true, true><<<dim3(Fc / 128, Mg / 128), 256, 0, stream>>>(
        hb, wtf1[0], b_ff1, ffb, Mg, Dc, Fc);
    gemm_mfma_n64<false, true><<<dim3(Dc / 64, Mg / 128), 256, 0, stream>>>(
        ffb, wtf2[0], b_ff2, tmpb, Mg, Fc, Dc);
    res_ln_kernel<<<Mg / 4, 256, 0, stream>>>(hb, tmpb, ln2_g, ln2_b);

    // ---- layers 1,2 --------------------------------------------------------
    for (int l = 1; l < 3; ++l) {
      gemm_mfma<false, true><<<dim3(3 * Dc / 128, Mg / 128), 256, 0, stream>>>(
          hb, wtq[l], b_qkv + (size_t)l * 3 * Dc, qkvb, Mg, Dc, 3 * Dc);
      transpose_v<<<dim3(Mg / 64, 8), 256, 0, stream>>>(qkvb, vt, VTSc);
      attn_mfma_kernel<false><<<dim3(Hc, Bc, np), 64, 0, stream>>>(
          qkvb, vt, VTSc, attno, p0, gs);
      gemm_mfma_n64<false, true><<<dim3(Dc / 64, Mg / 128), 256, 0, stream>>>(
          attno, wto[l], b_o + (size_t)l * Dc, tmpb, Mg, Dc, Dc);
      res_ln_kernel<<<Mg / 4, 256, 0, stream>>>(hb, tmpb, ln1_g + l * Dc, ln1_b + l * Dc);
      gemm_mfma<true, true><<<dim3(Fc / 128, Mg / 128), 256, 0, stream>>>(
          hb, wtf1[l], b_ff1 + (size_t)l * Fc, ffb, Mg, Dc, Fc);
      gemm_mfma_n64<false, true><<<dim3(Dc / 64, Mg / 128), 256, 0, stream>>>(
          ffb, wtf2[l], b_ff2 + (size_t)l * Dc, tmpb, Mg, Fc, Dc);
      res_ln_kernel<<<Mg / 4, 256, 0, stream>>>(hb, tmpb, ln2_g + l * Dc, ln2_b + l * Dc);
    }

    // ---- layer 3 (in-group part): diag gather, Q(diag), K/V(all), attn -----
    {
      const int l = 3;
      gather_diag<<<np * 16, 128, 0, stream>>>(hb, hbdiag, p0, gs, doff);
      gemm_mfma_n64<false, true><<<dim3(Dc / 64, M3 / 128), 256, 0, stream>>>(
          hbdiag + (size_t)doff * Dc, wtq[l], b_qkv + (size_t)l * 3 * Dc,
          qd + (size_t)doff * Dc, M3, Dc, Dc);
      gemm_mfma<false, true><<<dim3(2 * Dc / 128, Mg / 128), 256, 0, stream>>>(
          hb, wtq[l] + (size_t)512 * Dc, b_qkv + (size_t)l * 3 * Dc + 512,
          kv3, Mg, Dc, 2 * Dc);
      attn_diag_kernel<<<dim3(Hc, Bc, np), 64, 0, stream>>>(
          kv3, qd, attnd, p0, gs, doff);
    }
  }

  // ---- merged layer-3 tail on all 1024 diag rows ----------------------------
  {
    const int l = 3;
    gemm_mfma_n64<false, true><<<dim3(Dc / 64, DALLc / 128), 256, 0, stream>>>(
        attnd, wto[l], b_o + (size_t)l * Dc, tmpb, DALLc, Dc, Dc);
    res_ln_kernel<<<DALLc / 4, 256, 0, stream>>>(hbdiag, tmpb,
                                                 ln1_g + l * Dc, ln1_b + l * Dc);
    gemm_mfma<true, true><<<dim3(Fc / 128, DALLc / 128), 256, 0, stream>>>(
        hbdiag, wtf1[l], b_ff1 + (size_t)l * Fc, ffb, DALLc, Dc, Fc);
    gemm_mfma_n64<false, true><<<dim3(Dc / 64, DALLc / 128), 256, 0, stream>>>(
        ffb, wtf2[l], b_ff2 + (size_t)l * Dc, tmpb, DALLc, Fc, Dc);
    res_ln_kernel<<<DALLc / 4, 256, 0, stream>>>(hbdiag, tmpb,
                                                 ln2_g + l * Dc, ln2_b + l * Dc);
  }

  // ---- classifier: GEMM (relu) + 2-logit finisher ---------------------------
  gemm_mfma_n64<true, true><<<dim3(256 / 64, DALLc / 128), 256, 0, stream>>>(
      hbdiag, w1t, cls_b1, ffc, DALLc, Dc, 256);
  cls_fin_kernel<<<Bc * Tc, 64, 0, stream>>>(ffc, cls_w2, cls_b2, out);
}